// Round 1
// baseline (1185.307 us; speedup 1.0000x reference)
//
#include <hip/hip_runtime.h>

typedef unsigned short u16;
typedef __bf16 bf16x8 __attribute__((ext_vector_type(8)));
typedef unsigned short u16x8 __attribute__((ext_vector_type(8)));
typedef unsigned short u16x4 __attribute__((ext_vector_type(4)));
typedef float f32x4 __attribute__((ext_vector_type(4)));

#define K_DIM 2048
#define BM 128
#define BN 128
#define BK 32

// async global->LDS, 16B per lane; lds ptr must be wave-uniform base (+lane*16 in HW)
#define GLL16(g, l) __builtin_amdgcn_global_load_lds( \
    (const __attribute__((address_space(1))) void*)(g), \
    (__attribute__((address_space(3))) void*)(l), 16, 0, 0)

__device__ __forceinline__ u16 f2bf(float f) {
    unsigned int u = __builtin_bit_cast(unsigned int, f);
    u = (u + 0x7fffu + ((u >> 16) & 1u)) >> 16;   // RNE
    return (u16)u;
}
__device__ __forceinline__ float bf2f(u16 h) {
    unsigned int u = ((unsigned int)h) << 16;
    return __builtin_bit_cast(float, u);
}
__device__ __forceinline__ float softplus_f(float v) {
    return fmaxf(v, 0.0f) + log1pf(expf(-fabsf(v)));
}

// ---------------- pack f32 -> bf16, 4 elems/thread ----------------
__global__ void pack_kernel(const float* __restrict__ src, u16* __restrict__ dst, int n4) {
    int i = blockIdx.x * blockDim.x + threadIdx.x;
    if (i >= n4) return;
    float4 v = ((const float4*)src)[i];
    u16x4 o;
    o[0] = f2bf(v.x); o[1] = f2bf(v.y); o[2] = f2bf(v.z); o[3] = f2bf(v.w);
    ((u16x4*)dst)[i] = o;
}

// ---------------- fused GEMM: C = A * B^T with rms/softplus epilogue ----------------
// A = xb [16384, 2048] bf16 row-major
// B = wb [8192, 2048] bf16 row-major (rows 0..2047: Wq, 2048..: Wk, then Wsq, Wsk)
// outputs: qb,kb (rms-normed bf16), sqb,skb (softplus bf16), each [16384, 2048]
__global__ __launch_bounds__(256) void gemm_fused(
    const u16* __restrict__ xb, const u16* __restrict__ wb,
    u16* __restrict__ qb, u16* __restrict__ kb,
    u16* __restrict__ sqb, u16* __restrict__ skb)
{
    __shared__ u16 Als[BM * BK];
    __shared__ u16 Bls[BM * BK];
    __shared__ float ss[BM];

    const int tid  = threadIdx.x;
    const int lane = tid & 63;
    const int wave = tid >> 6;
    const int wm = wave >> 1;   // 2x2 wave grid, each wave 64x64
    const int wn = wave & 1;
    const int gm0 = blockIdx.y * BM;
    const int gn0 = blockIdx.x * BN;

    // staging: chunk c = pass*256 + tid; row = c>>2, koffset = (c&3)*8 bf16
    const int r0 = tid >> 2;
    const int kc = (tid & 3) * 8;
    const u16* gA0 = xb + (size_t)(gm0 + r0) * K_DIM + kc;
    const u16* gA1 = gA0 + (size_t)64 * K_DIM;
    const u16* gB0 = wb + (size_t)(gn0 + r0) * K_DIM + kc;
    const u16* gB1 = gB0 + (size_t)64 * K_DIM;
    char* lA0 = (char*)Als + wave * 1024;
    char* lA1 = (char*)Als + 4096 + wave * 1024;
    char* lB0 = (char*)Bls + wave * 1024;
    char* lB1 = (char*)Bls + 4096 + wave * 1024;

    f32x4 acc[4][4] = {};

    const int arow = wm * 64 + (lane & 15);  // + i*16
    const int brow = wn * 64 + (lane & 15);  // + j*16
    const int koff = (lane >> 4) * 8;        // A[m][k=quad*8+j] layout

    for (int kt = 0; kt < K_DIM / BK; ++kt) {
        GLL16(gA0, lA0); GLL16(gA1, lA1);
        GLL16(gB0, lB0); GLL16(gB1, lB1);
        gA0 += BK; gA1 += BK; gB0 += BK; gB1 += BK;
        __syncthreads();   // drains vmcnt(0) then barrier

        bf16x8 a[4], b[4];
#pragma unroll
        for (int i = 0; i < 4; ++i)
            a[i] = __builtin_bit_cast(bf16x8, *(const u16x8*)&Als[(arow + i * 16) * BK + koff]);
#pragma unroll
        for (int j = 0; j < 4; ++j)
            b[j] = __builtin_bit_cast(bf16x8, *(const u16x8*)&Bls[(brow + j * 16) * BK + koff]);
#pragma unroll
        for (int i = 0; i < 4; ++i)
#pragma unroll
            for (int j = 0; j < 4; ++j)
                acc[i][j] = __builtin_amdgcn_mfma_f32_16x16x32_bf16(a[i], b[j], acc[i][j], 0, 0, 0);
        __syncthreads();
    }

    // ---------------- epilogue ----------------
    const int which = gn0 >> 11;          // 0:q 1:k 2:sq 3:sk (block-uniform)
    if (tid < BM) ss[tid] = 0.0f;
    __syncthreads();

    const int mbase = wm * 64 + (lane >> 4) * 4;     // + i*16 + r
    const int col0  = (gn0 & 2047) + wn * 64 + (lane & 15);  // + j*16

    if (which < 2) {
        // per-row sum of squares over the tile's 128 cols (== one head, Dh=128)
#pragma unroll
        for (int i = 0; i < 4; ++i) {
#pragma unroll
            for (int r = 0; r < 4; ++r) {
                float s = acc[i][0][r] * acc[i][0][r] + acc[i][1][r] * acc[i][1][r]
                        + acc[i][2][r] * acc[i][2][r] + acc[i][3][r] * acc[i][3][r];
                s += __shfl_xor(s, 1, 64);
                s += __shfl_xor(s, 2, 64);
                s += __shfl_xor(s, 4, 64);
                s += __shfl_xor(s, 8, 64);
                if ((lane & 15) == 0) atomicAdd(&ss[mbase + i * 16 + r], s);
            }
        }
        __syncthreads();
    }

    u16* ob = (which == 0) ? qb : (which == 1) ? kb : (which == 2) ? sqb : skb;
#pragma unroll
    for (int i = 0; i < 4; ++i) {
#pragma unroll
        for (int r = 0; r < 4; ++r) {
            int m = mbase + i * 16 + r;
            size_t rowbase = (size_t)(gm0 + m) * 2048;
            float scale = 1.0f;
            if (which < 2)
                scale = rsqrtf(ss[m] * (1.0f / 128.0f) + 1.1920929e-07f);
#pragma unroll
            for (int j = 0; j < 4; ++j) {
                float v = acc[i][j][r];
                v = (which < 2) ? v * scale : softplus_f(v);
                ob[rowbase + col0 + j * 16] = f2bf(v);
            }
        }
    }
}

// ---------------- interp + multiply ----------------
// out[b,t,h,d] = interp(q, posq) * interp(k, posk);  layout [B*T, 2048] = idx
__global__ void interp_mul(const u16* __restrict__ qb, const u16* __restrict__ kb,
                           const u16* __restrict__ sqb, const u16* __restrict__ skb,
                           float* __restrict__ out)
{
    size_t idx = (size_t)blockIdx.x * 256 + threadIdx.x;   // exact: 131072*256 = 2^25
    int c = (int)(idx & 2047);
    size_t bt = idx >> 11;
    int t = (int)(bt & 4095);
    float tf = (float)t;

    float sqv = bf2f(sqb[idx]);
    float skv = bf2f(skb[idx]);
    float pq = fminf(fmaxf(tf - sqv, 0.0f), tf);
    float pk = fminf(fmaxf(tf - skv, 0.0f), tf);
    float pqf = floorf(pq), pkf = floorf(pk);
    int q0i = (int)pqf, k0i = (int)pkf;
    int q1i = min(q0i + 1, 4095), k1i = min(k0i + 1, 4095);
    float fq = pq - pqf, fk = pk - pkf;

    size_t rb = (idx >> 23) << 23;   // b * T * 2048  (T*2048 = 2^23)
    size_t o = rb + (size_t)c;
    float q0 = bf2f(qb[o + ((size_t)q0i << 11)]);
    float q1 = bf2f(qb[o + ((size_t)q1i << 11)]);
    float k0 = bf2f(kb[o + ((size_t)k0i << 11)]);
    float k1 = bf2f(kb[o + ((size_t)k1i << 11)]);
    float qd = q0 + (q1 - q0) * fq;
    float kd = k0 + (k1 - k0) * fk;
    out[idx] = qd * kd;
}

extern "C" void kernel_launch(void* const* d_in, const int* in_sizes, int n_in,
                              void* d_out, int out_size, void* d_ws, size_t ws_size,
                              hipStream_t stream) {
    const float* x   = (const float*)d_in[0];
    const float* Wq  = (const float*)d_in[1];
    const float* Wk  = (const float*)d_in[2];
    const float* Wsq = (const float*)d_in[3];
    const float* Wsk = (const float*)d_in[4];
    float* out = (float*)d_out;

    // ws layout (bytes): xb 64MB | wb 32MB | qb 64MB | kb 64MB | sqb 64MB | skb 64MB = 352MB
    const size_t NEED = 369098752;
    if (ws_size < NEED) return;   // loud failure (absmax == ref absmax) -> ws too small
    char* ws = (char*)d_ws;
    u16* xb  = (u16*)(ws);
    u16* wb  = (u16*)(ws + 67108864);
    u16* qb  = (u16*)(ws + 100663296);
    u16* kb  = (u16*)(ws + 167772160);
    u16* sqb = (u16*)(ws + 234881024);
    u16* skb = (u16*)(ws + 301989888);

    pack_kernel<<<32768, 256, 0, stream>>>(x,   xb, 8388608);
    pack_kernel<<<4096,  256, 0, stream>>>(Wq,  wb,            1048576);
    pack_kernel<<<4096,  256, 0, stream>>>(Wk,  wb + 4194304,  1048576);
    pack_kernel<<<4096,  256, 0, stream>>>(Wsq, wb + 8388608,  1048576);
    pack_kernel<<<4096,  256, 0, stream>>>(Wsk, wb + 12582912, 1048576);

    dim3 ggrid(64, 128);   // N tiles x M tiles
    gemm_fused<<<ggrid, 256, 0, stream>>>(xb, wb, qb, kb, sqb, skb);

    interp_mul<<<131072, 256, 0, stream>>>(qb, kb, sqb, skb, out);
}

// Round 2
// 1171.958 us; speedup vs baseline: 1.0114x; 1.0114x over previous
//
#include <hip/hip_runtime.h>

typedef unsigned short u16;
typedef __bf16 bf16x8 __attribute__((ext_vector_type(8)));
typedef unsigned short u16x8 __attribute__((ext_vector_type(8)));
typedef unsigned short u16x4 __attribute__((ext_vector_type(4)));
typedef float f32x4 __attribute__((ext_vector_type(4)));

#define K_DIM 2048
#define BM 128
#define BN 128
#define BK 32

// async global->LDS, 16B per lane; lds ptr must be wave-uniform base (+lane*16 in HW)
#define GLL16(g, l) __builtin_amdgcn_global_load_lds( \
    (const __attribute__((address_space(1))) void*)(g), \
    (__attribute__((address_space(3))) void*)(l), 16, 0, 0)

__device__ __forceinline__ u16 f2bf(float f) {
    unsigned int u = __builtin_bit_cast(unsigned int, f);
    u = (u + 0x7fffu + ((u >> 16) & 1u)) >> 16;   // RNE
    return (u16)u;
}
__device__ __forceinline__ float bf2f(u16 h) {
    unsigned int u = ((unsigned int)h) << 16;
    return __builtin_bit_cast(float, u);
}
__device__ __forceinline__ float softplus_f(float v) {
    return fmaxf(v, 0.0f) + log1pf(expf(-fabsf(v)));
}

// ---------------- pack f32 -> bf16, 4 elems/thread ----------------
__global__ void pack_kernel(const float* __restrict__ src, u16* __restrict__ dst, int n4) {
    int i = blockIdx.x * blockDim.x + threadIdx.x;
    if (i >= n4) return;
    float4 v = ((const float4*)src)[i];
    u16x4 o;
    o[0] = f2bf(v.x); o[1] = f2bf(v.y); o[2] = f2bf(v.z); o[3] = f2bf(v.w);
    ((u16x4*)dst)[i] = o;
}

// ---------------- fused GEMM: C = A * B^T with rms/softplus epilogue ----------------
// LDS layout is XOR/add-swizzled to kill the 8-way ds_read_b128 bank conflict:
// chunk (row r, q) of a k-tile lives at in-group position (r&15)*4 + ((q + ((r&15)>>1))&3),
// group = 16 rows = 64 chunks. Staging picks the source chunk so the lane-ordered
// global_load_lds write realizes exactly this placement.
__global__ __launch_bounds__(256) void gemm_fused(
    const u16* __restrict__ xb, const u16* __restrict__ wb,
    u16* __restrict__ qb, u16* __restrict__ kb,
    u16* __restrict__ sqb, u16* __restrict__ skb)
{
    __shared__ u16 Als[BM * BK];
    __shared__ u16 Bls[BM * BK];
    __shared__ float ss[BM];

    const int tid  = threadIdx.x;
    const int lane = tid & 63;
    const int wave = tid >> 6;
    const int wm = wave >> 1;   // 2x2 wave grid, each wave 64x64
    const int wn = wave & 1;
    const int gm0 = blockIdx.y * BM;
    const int gn0 = blockIdx.x * BN;

    // staging: thread tid writes LDS 16B slot tid (wave-uniform base + lane*16).
    // slot tid = group (tid>>6? no: rows r0=tid>>2), within-group j = tid&3.
    // stored chunk must be q = (j - ((r&15)>>1)) & 3  ->  swizzled source column.
    const int r0 = tid >> 2;
    const int qs = ((tid & 3) - ((tid >> 3) & 3)) & 3;   // source chunk index
    const int kc = qs * 8;                               // u16 offset within 32-elem k-slice
    const u16* gA0 = xb + (size_t)(gm0 + r0) * K_DIM + kc;
    const u16* gA1 = gA0 + (size_t)64 * K_DIM;
    const u16* gB0 = wb + (size_t)(gn0 + r0) * K_DIM + kc;
    const u16* gB1 = gB0 + (size_t)64 * K_DIM;
    char* lA0 = (char*)Als + wave * 1024;
    char* lA1 = (char*)Als + 4096 + wave * 1024;
    char* lB0 = (char*)Bls + wave * 1024;
    char* lB1 = (char*)Bls + 4096 + wave * 1024;

    f32x4 acc[4][4] = {};

    const int mr = lane & 15;
    const int q  = lane >> 4;
    const int s  = (q + (mr >> 1)) & 3;                  // swizzled read position
    const int fragoff = mr * 32 + s * 8;                 // u16 offset within 16-row group

    for (int kt = 0; kt < K_DIM / BK; ++kt) {
        GLL16(gA0, lA0); GLL16(gA1, lA1);
        GLL16(gB0, lB0); GLL16(gB1, lB1);
        gA0 += BK; gA1 += BK; gB0 += BK; gB1 += BK;
        __syncthreads();   // drains vmcnt(0) then barrier

        bf16x8 a[4], b[4];
#pragma unroll
        for (int i = 0; i < 4; ++i)
            a[i] = __builtin_bit_cast(bf16x8, *(const u16x8*)&Als[(wm * 4 + i) * 512 + fragoff]);
#pragma unroll
        for (int j = 0; j < 4; ++j)
            b[j] = __builtin_bit_cast(bf16x8, *(const u16x8*)&Bls[(wn * 4 + j) * 512 + fragoff]);
#pragma unroll
        for (int i = 0; i < 4; ++i)
#pragma unroll
            for (int j = 0; j < 4; ++j)
                acc[i][j] = __builtin_amdgcn_mfma_f32_16x16x32_bf16(a[i], b[j], acc[i][j], 0, 0, 0);
        __syncthreads();
    }

    // ---------------- epilogue ----------------
    const int which = gn0 >> 11;          // 0:q 1:k 2:sq 3:sk (block-uniform)
    if (tid < BM) ss[tid] = 0.0f;
    __syncthreads();

    const int mbase = wm * 64 + (lane >> 4) * 4;     // + i*16 + r
    const int col0  = (gn0 & 2047) + wn * 64 + (lane & 15);  // + j*16

    if (which < 2) {
        // per-row sum of squares over the tile's 128 cols (== one head, Dh=128)
#pragma unroll
        for (int i = 0; i < 4; ++i) {
#pragma unroll
            for (int r = 0; r < 4; ++r) {
                float sv = acc[i][0][r] * acc[i][0][r] + acc[i][1][r] * acc[i][1][r]
                         + acc[i][2][r] * acc[i][2][r] + acc[i][3][r] * acc[i][3][r];
                sv += __shfl_xor(sv, 1, 64);
                sv += __shfl_xor(sv, 2, 64);
                sv += __shfl_xor(sv, 4, 64);
                sv += __shfl_xor(sv, 8, 64);
                if ((lane & 15) == 0) atomicAdd(&ss[mbase + i * 16 + r], sv);
            }
        }
        __syncthreads();
    }

    u16* ob = (which == 0) ? qb : (which == 1) ? kb : (which == 2) ? sqb : skb;
#pragma unroll
    for (int i = 0; i < 4; ++i) {
#pragma unroll
        for (int r = 0; r < 4; ++r) {
            int m = mbase + i * 16 + r;
            size_t rowbase = (size_t)(gm0 + m) * 2048;
            float scale = 1.0f;
            if (which < 2)
                scale = rsqrtf(ss[m] * (1.0f / 128.0f) + 1.1920929e-07f);
#pragma unroll
            for (int j = 0; j < 4; ++j) {
                float v = acc[i][j][r];
                v = (which < 2) ? v * scale : softplus_f(v);
                ob[rowbase + col0 + j * 16] = f2bf(v);
            }
        }
    }
}

// ---------------- interp + multiply ----------------
// out[b,t,h,d] = interp(q, posq) * interp(k, posk);  layout [B*T, 2048] = idx
__global__ void interp_mul(const u16* __restrict__ qb, const u16* __restrict__ kb,
                           const u16* __restrict__ sqb, const u16* __restrict__ skb,
                           float* __restrict__ out)
{
    size_t idx = (size_t)blockIdx.x * 256 + threadIdx.x;   // exact: 131072*256 = 2^25
    int c = (int)(idx & 2047);
    size_t bt = idx >> 11;
    int t = (int)(bt & 4095);
    float tf = (float)t;

    float sqv = bf2f(sqb[idx]);
    float skv = bf2f(skb[idx]);
    float pq = fminf(fmaxf(tf - sqv, 0.0f), tf);
    float pk = fminf(fmaxf(tf - skv, 0.0f), tf);
    float pqf = floorf(pq), pkf = floorf(pk);
    int q0i = (int)pqf, k0i = (int)pkf;
    int q1i = min(q0i + 1, 4095), k1i = min(k0i + 1, 4095);
    float fq = pq - pqf, fk = pk - pkf;

    size_t rb = (idx >> 23) << 23;   // b * T * 2048  (T*2048 = 2^23)
    size_t o = rb + (size_t)c;
    float q0 = bf2f(qb[o + ((size_t)q0i << 11)]);
    float q1 = bf2f(qb[o + ((size_t)q1i << 11)]);
    float k0 = bf2f(kb[o + ((size_t)k0i << 11)]);
    float k1 = bf2f(kb[o + ((size_t)k1i << 11)]);
    float qd = q0 + (q1 - q0) * fq;
    float kd = k0 + (k1 - k0) * fk;
    out[idx] = qd * kd;
}

extern "C" void kernel_launch(void* const* d_in, const int* in_sizes, int n_in,
                              void* d_out, int out_size, void* d_ws, size_t ws_size,
                              hipStream_t stream) {
    const float* x   = (const float*)d_in[0];
    const float* Wq  = (const float*)d_in[1];
    const float* Wk  = (const float*)d_in[2];
    const float* Wsq = (const float*)d_in[3];
    const float* Wsk = (const float*)d_in[4];
    float* out = (float*)d_out;

    // ws layout (bytes): xb 64MB | wb 32MB | qb 64MB | kb 64MB | sqb 64MB | skb 64MB = 352MB
    const size_t NEED = 369098752;
    if (ws_size < NEED) return;   // loud failure -> ws too small
    char* ws = (char*)d_ws;
    u16* xb  = (u16*)(ws);
    u16* wb  = (u16*)(ws + 67108864);
    u16* qb  = (u16*)(ws + 100663296);
    u16* kb  = (u16*)(ws + 167772160);
    u16* sqb = (u16*)(ws + 234881024);
    u16* skb = (u16*)(ws + 301989888);

    pack_kernel<<<32768, 256, 0, stream>>>(x,   xb, 8388608);
    pack_kernel<<<4096,  256, 0, stream>>>(Wq,  wb,            1048576);
    pack_kernel<<<4096,  256, 0, stream>>>(Wk,  wb + 4194304,  1048576);
    pack_kernel<<<4096,  256, 0, stream>>>(Wsq, wb + 8388608,  1048576);
    pack_kernel<<<4096,  256, 0, stream>>>(Wsk, wb + 12582912, 1048576);

    dim3 ggrid(64, 128);   // N tiles x M tiles
    gemm_fused<<<ggrid, 256, 0, stream>>>(xb, wb, qb, kb, sqb, skb);

    interp_mul<<<131072, 256, 0, stream>>>(qb, kb, sqb, skb, out);
}